// Round 1
// baseline (2470.283 us; speedup 1.0000x reference)
//
#include <hip/hip_runtime.h>
#include <math.h>

#define BB 4096
#define HH 4
#define NN 1024
#define DHD 256
#define DECAY 0.99f
#define OMD 0.01f
#define EPSV 1e-5f

// ---------------------------------------------------------------------------
// wsq[row] = sum_k emb[row][k]^2   for all H*N rows (one wave per row)
// ---------------------------------------------------------------------------
__global__ __launch_bounds__(256) void k_wsq(const float* __restrict__ emb,
                                             float* __restrict__ wsq) {
    int wave = threadIdx.x >> 6;
    int lane = threadIdx.x & 63;
    int row  = blockIdx.x * 4 + wave;            // [0, H*N)
    const float* w = emb + (size_t)row * DHD;
    float4 v = *(const float4*)(w + lane * 4);   // 64 lanes * 4 = 256 = DH
    float s = v.x * v.x + v.y * v.y + v.z * v.z + v.w * v.w;
    for (int off = 32; off; off >>= 1) s += __shfl_down(s, off);
    if (lane == 0) wsq[row] = s;
}

// ---------------------------------------------------------------------------
// logits[i][j] = 2*sum_k X[i][k]*W[j][k] - wsq[j] (+ sum_k P[i][k]*T[j][k])
// X: rows of length DH with stride H*DH. W: N x DH. P: B x N. T: N x N.
// Tile 64x64, BK=16, 256 threads, 4x4 micro-tile.
// ---------------------------------------------------------------------------
template <int HASPREV>
__global__ __launch_bounds__(256) void k_logits(const float* __restrict__ X,
                                                const float* __restrict__ W,
                                                const float* __restrict__ wsq,
                                                const float* __restrict__ P,
                                                const float* __restrict__ T,
                                                float* __restrict__ out) {
    __shared__ float As[16][65];
    __shared__ float Bs[16][65];
    const int t  = threadIdx.x;
    const int tx = t & 15, ty = t >> 4;
    const int j0 = blockIdx.x * 64;   // N tile
    const int i0 = blockIdx.y * 64;   // B tile
    const int lr = t >> 2;            // 0..63
    const int lk = (t & 3) * 4;       // 0,4,8,12
    const int XLD = HH * DHD;

    float acc[4][4] = {};

    // phase 1: 2 * X . W^T  (K = DH)
    for (int k0 = 0; k0 < DHD; k0 += 16) {
        float4 av = *(const float4*)(X + (size_t)(i0 + lr) * XLD + k0 + lk);
        float4 bv = *(const float4*)(W + (size_t)(j0 + lr) * DHD + k0 + lk);
        As[lk + 0][lr] = 2.f * av.x; As[lk + 1][lr] = 2.f * av.y;
        As[lk + 2][lr] = 2.f * av.z; As[lk + 3][lr] = 2.f * av.w;
        Bs[lk + 0][lr] = bv.x; Bs[lk + 1][lr] = bv.y;
        Bs[lk + 2][lr] = bv.z; Bs[lk + 3][lr] = bv.w;
        __syncthreads();
#pragma unroll
        for (int kk = 0; kk < 16; kk++) {
            float a[4], b[4];
#pragma unroll
            for (int u = 0; u < 4; u++) a[u] = As[kk][ty * 4 + u];
#pragma unroll
            for (int v = 0; v < 4; v++) b[v] = Bs[kk][tx * 4 + v];
#pragma unroll
            for (int u = 0; u < 4; u++)
#pragma unroll
                for (int v = 0; v < 4; v++) acc[u][v] += a[u] * b[v];
        }
        __syncthreads();
    }

    // phase 2: + P . T^T  (K = N)
    if (HASPREV) {
        for (int k0 = 0; k0 < NN; k0 += 16) {
            float4 av = *(const float4*)(P + (size_t)(i0 + lr) * NN + k0 + lk);
            float4 bv = *(const float4*)(T + (size_t)(j0 + lr) * NN + k0 + lk);
            As[lk + 0][lr] = av.x; As[lk + 1][lr] = av.y;
            As[lk + 2][lr] = av.z; As[lk + 3][lr] = av.w;
            Bs[lk + 0][lr] = bv.x; Bs[lk + 1][lr] = bv.y;
            Bs[lk + 2][lr] = bv.z; Bs[lk + 3][lr] = bv.w;
            __syncthreads();
#pragma unroll
            for (int kk = 0; kk < 16; kk++) {
                float a[4], b[4];
#pragma unroll
                for (int u = 0; u < 4; u++) a[u] = As[kk][ty * 4 + u];
#pragma unroll
                for (int v = 0; v < 4; v++) b[v] = Bs[kk][tx * 4 + v];
#pragma unroll
                for (int u = 0; u < 4; u++)
#pragma unroll
                    for (int v = 0; v < 4; v++) acc[u][v] += a[u] * b[v];
            }
            __syncthreads();
        }
    }

#pragma unroll
    for (int u = 0; u < 4; u++) {
        int i = i0 + ty * 4 + u;
#pragma unroll
        for (int v = 0; v < 4; v++) {
            int j = j0 + tx * 4 + v;
            out[(size_t)i * NN + j] = acc[u][v] - wsq[j];
        }
    }
}

// ---------------------------------------------------------------------------
// In-place row softmax over N=1024, argmax -> codes (as float). Block per row.
// ---------------------------------------------------------------------------
__global__ __launch_bounds__(256) void k_softmax(float* __restrict__ L,
                                                 float* __restrict__ codes,
                                                 int h) {
    __shared__ float smax[256];
    __shared__ int   sidx[256];
    const int i = blockIdx.x;
    const int t = threadIdx.x;
    float* row = L + (size_t)i * NN;

    float v[4];
    float m = -INFINITY;
    int   mi = 0;
#pragma unroll
    for (int q = 0; q < 4; q++) {
        int j = q * 256 + t;
        v[q] = row[j];
        if (v[q] > m) { m = v[q]; mi = j; }   // ascending j: strict > keeps lowest index
    }
    smax[t] = m; sidx[t] = mi;
    __syncthreads();
    for (int s = 128; s; s >>= 1) {
        if (t < s) {
            float o = smax[t + s]; int oi = sidx[t + s];
            if (o > smax[t] || (o == smax[t] && oi < sidx[t])) { smax[t] = o; sidx[t] = oi; }
        }
        __syncthreads();
    }
    m = smax[0];
    int code = sidx[0];
    __syncthreads();   // everyone read smax[0] before reuse

    float s = 0.f;
#pragma unroll
    for (int q = 0; q < 4; q++) { v[q] = expf(v[q] - m); s += v[q]; }
    smax[t] = s;
    __syncthreads();
    for (int ss = 128; ss; ss >>= 1) {
        if (t < ss) smax[t] += smax[t + ss];
        __syncthreads();
    }
    float inv = 1.0f / smax[0];
#pragma unroll
    for (int q = 0; q < 4; q++) row[q * 256 + t] = v[q] * inv;

    if (t == 0) codes[(size_t)i * HH + h] = (float)code;
}

// ---------------------------------------------------------------------------
// colsum[j] += sum over a 256-row slab of P[i][j]
// ---------------------------------------------------------------------------
__global__ __launch_bounds__(256) void k_colsum(const float* __restrict__ P,
                                                float* __restrict__ colsum) {
    int j  = blockIdx.x * 256 + threadIdx.x;
    int i0 = blockIdx.y * 256;
    float s = 0.f;
    for (int i = i0; i < i0 + 256; i++) s += P[(size_t)i * NN + j];
    atomicAdd(&colsum[j], s);
}

// ---------------------------------------------------------------------------
// csn[j] = (cs[j]+eps)/(n+N*eps)*n, cs = cluster_size*DECAY + 0.01*colsum
// single block of 1024 threads
// ---------------------------------------------------------------------------
__global__ __launch_bounds__(1024) void k_cs(const float* __restrict__ cluster_size,
                                             const float* __restrict__ colsum,
                                             float* __restrict__ csn, int h) {
    __shared__ float red[1024];
    int j = threadIdx.x;
    float cs = cluster_size[h * NN + j] * DECAY + OMD * colsum[j];
    red[j] = cs;
    __syncthreads();
    for (int s = 512; s; s >>= 1) {
        if (j < s) red[j] += red[j + s];
        __syncthreads();
    }
    float n = red[0];
    csn[j] = (cs + EPSV) / (n + NN * EPSV) * n;
}

// ---------------------------------------------------------------------------
// new_w[j][k] = (ema[j][k]*DECAY + 0.01 * sum_i P[i][j]*X[i][k]) / csn[j]
// ---------------------------------------------------------------------------
__global__ __launch_bounds__(256) void k_neww(const float* __restrict__ P,
                                              const float* __restrict__ X,
                                              const float* __restrict__ ema,
                                              const float* __restrict__ csn,
                                              float* __restrict__ neww) {
    __shared__ float As[16][65];   // As[i_k][j]
    __shared__ float Bs[16][65];   // Bs[i_k][k]
    const int t   = threadIdx.x;
    const int tx  = t & 15, ty = t >> 4;
    const int k0c = blockIdx.x * 64;   // DH tile
    const int j0  = blockIdx.y * 64;   // N tile
    const int lkk = t >> 4;            // 0..15
    const int lm4 = (t & 15) * 4;      // 0..60
    const int XLD = HH * DHD;

    float acc[4][4] = {};
    for (int i0 = 0; i0 < BB; i0 += 16) {
        float4 av = *(const float4*)(P + (size_t)(i0 + lkk) * NN + j0 + lm4);
        float4 bv = *(const float4*)(X + (size_t)(i0 + lkk) * XLD + k0c + lm4);
        As[lkk][lm4 + 0] = av.x; As[lkk][lm4 + 1] = av.y;
        As[lkk][lm4 + 2] = av.z; As[lkk][lm4 + 3] = av.w;
        Bs[lkk][lm4 + 0] = bv.x; Bs[lkk][lm4 + 1] = bv.y;
        Bs[lkk][lm4 + 2] = bv.z; Bs[lkk][lm4 + 3] = bv.w;
        __syncthreads();
#pragma unroll
        for (int kk = 0; kk < 16; kk++) {
            float a[4], b[4];
#pragma unroll
            for (int u = 0; u < 4; u++) a[u] = As[kk][ty * 4 + u];
#pragma unroll
            for (int v = 0; v < 4; v++) b[v] = Bs[kk][tx * 4 + v];
#pragma unroll
            for (int u = 0; u < 4; u++)
#pragma unroll
                for (int v = 0; v < 4; v++) acc[u][v] += a[u] * b[v];
        }
        __syncthreads();
    }
#pragma unroll
    for (int u = 0; u < 4; u++) {
        int j = j0 + ty * 4 + u;
        float inv = 1.0f / csn[j];
#pragma unroll
        for (int v = 0; v < 4; v++) {
            int k = k0c + tx * 4 + v;
            neww[(size_t)j * DHD + k] =
                (ema[(size_t)j * DHD + k] * DECAY + OMD * acc[u][v]) * inv;
        }
    }
}

// ---------------------------------------------------------------------------
// quant[i][h*DH + k] = sum_j P[i][j] * Wn[j][k]
// ---------------------------------------------------------------------------
__global__ __launch_bounds__(256) void k_quant(const float* __restrict__ P,
                                               const float* __restrict__ Wn,
                                               float* __restrict__ outq, int h) {
    __shared__ float As[16][65];   // As[j_k][i]
    __shared__ float Bs[16][65];   // Bs[j_k][k]
    const int t   = threadIdx.x;
    const int tx  = t & 15, ty = t >> 4;
    const int k0c = blockIdx.x * 64;  // DH tile
    const int i0  = blockIdx.y * 64;  // B tile
    const int lr  = t >> 2, lk4 = (t & 3) * 4;   // A trans-load
    const int lkk = t >> 4, ln4 = (t & 15) * 4;  // B direct-load

    float acc[4][4] = {};
    for (int j0 = 0; j0 < NN; j0 += 16) {
        float4 av = *(const float4*)(P + (size_t)(i0 + lr) * NN + j0 + lk4);
        As[lk4 + 0][lr] = av.x; As[lk4 + 1][lr] = av.y;
        As[lk4 + 2][lr] = av.z; As[lk4 + 3][lr] = av.w;
        float4 bv = *(const float4*)(Wn + (size_t)(j0 + lkk) * DHD + k0c + ln4);
        Bs[lkk][ln4 + 0] = bv.x; Bs[lkk][ln4 + 1] = bv.y;
        Bs[lkk][ln4 + 2] = bv.z; Bs[lkk][ln4 + 3] = bv.w;
        __syncthreads();
#pragma unroll
        for (int kk = 0; kk < 16; kk++) {
            float a[4], b[4];
#pragma unroll
            for (int u = 0; u < 4; u++) a[u] = As[kk][ty * 4 + u];
#pragma unroll
            for (int v = 0; v < 4; v++) b[v] = Bs[kk][tx * 4 + v];
#pragma unroll
            for (int u = 0; u < 4; u++)
#pragma unroll
                for (int v = 0; v < 4; v++) acc[u][v] += a[u] * b[v];
        }
        __syncthreads();
    }
#pragma unroll
    for (int u = 0; u < 4; u++) {
        int i = i0 + ty * 4 + u;
#pragma unroll
        for (int v = 0; v < 4; v++) {
            int k = k0c + tx * 4 + v;
            outq[(size_t)i * (HH * DHD) + h * DHD + k] = acc[u][v];
        }
    }
}

// ---------------------------------------------------------------------------
// loss[i] = 1.25 * mean_k (q[i][k] - x[i][k])^2   over H*DH = 1024
// ---------------------------------------------------------------------------
__global__ __launch_bounds__(256) void k_loss(const float* __restrict__ x,
                                              const float* __restrict__ q,
                                              float* __restrict__ loss) {
    __shared__ float red[256];
    const int i = blockIdx.x, t = threadIdx.x;
    const float* xr = x + (size_t)i * 1024;
    const float* qr = q + (size_t)i * 1024;
    float s = 0.f;
#pragma unroll
    for (int q4 = 0; q4 < 4; q4++) {
        int k = q4 * 256 + t;
        float d = qr[k] - xr[k];
        s += d * d;
    }
    red[t] = s;
    __syncthreads();
    for (int ss = 128; ss; ss >>= 1) {
        if (t < ss) red[t] += red[t + ss];
        __syncthreads();
    }
    if (t == 0) loss[i] = 1.25f * red[0] * (1.0f / 1024.0f);
}

// ---------------------------------------------------------------------------
extern "C" void kernel_launch(void* const* d_in, const int* in_sizes, int n_in,
                              void* d_out, int out_size, void* d_ws, size_t ws_size,
                              hipStream_t stream) {
    const float* inputs = (const float*)d_in[0];   // B x (H*DH)
    const float* emb    = (const float*)d_in[1];   // H x N x DH
    const float* ema    = (const float*)d_in[2];   // H x N x DH
    const float* csz    = (const float*)d_in[3];   // H x N
    const float* trans  = (const float*)d_in[4];   // H x N x N

    float* out   = (float*)d_out;
    float* loss  = out;                               // B
    float* quant = out + BB;                          // B*H*DH
    float* codes = out + BB + (size_t)BB * HH * DHD;  // B*H

    float* ws     = (float*)d_ws;
    float* P0     = ws;                           // B*N
    float* P1     = P0 + (size_t)BB * NN;         // B*N
    float* wsq    = P1 + (size_t)BB * NN;         // H*N
    float* colsum = wsq + HH * NN;                // N
    float* csn    = colsum + NN;                  // N
    float* neww   = csn + NN;                     // N*DH

    k_wsq<<<HH * NN / 4, 256, 0, stream>>>(emb, wsq);

    float* Pprev = P1;
    float* Pcur  = P0;
    for (int h = 0; h < HH; h++) {
        const float* X = inputs + h * DHD;
        const float* W = emb + (size_t)h * NN * DHD;
        if (h == 0)
            k_logits<0><<<dim3(NN / 64, BB / 64), 256, 0, stream>>>(
                X, W, wsq + h * NN, nullptr, nullptr, Pcur);
        else
            k_logits<1><<<dim3(NN / 64, BB / 64), 256, 0, stream>>>(
                X, W, wsq + h * NN, Pprev, trans + (size_t)h * NN * NN, Pcur);

        k_softmax<<<BB, 256, 0, stream>>>(Pcur, codes, h);

        hipMemsetAsync(colsum, 0, NN * sizeof(float), stream);
        k_colsum<<<dim3(NN / 256, 16), 256, 0, stream>>>(Pcur, colsum);
        k_cs<<<1, NN, 0, stream>>>(csz, colsum, csn, h);

        k_neww<<<dim3(DHD / 64, NN / 64), 256, 0, stream>>>(
            Pcur, X, ema + (size_t)h * NN * DHD, csn, neww);
        k_quant<<<dim3(DHD / 64, BB / 64), 256, 0, stream>>>(Pcur, neww, quant, h);

        float* tmp = Pprev; Pprev = Pcur; Pcur = tmp;
    }

    k_loss<<<BB, 256, 0, stream>>>(inputs, quant, loss);
}

// Round 2
// 1288.108 us; speedup vs baseline: 1.9178x; 1.9178x over previous
//
#include <hip/hip_runtime.h>
#include <math.h>

#define BB 4096
#define HH 4
#define NN 1024
#define DHD 256
#define DECAY 0.99f
#define OMD 0.01f
#define EPSV 1e-5f
#define PAD 68   // LDS row stride in floats: 68*4=272 B, 16B-aligned rows -> ds_read_b128

// ---------------------------------------------------------------------------
// wsq[row] = sum_k emb[row][k]^2   for all H*N rows (one wave per row)
// ---------------------------------------------------------------------------
__global__ __launch_bounds__(256) void k_wsq(const float* __restrict__ emb,
                                             float* __restrict__ wsq) {
    int wave = threadIdx.x >> 6;
    int lane = threadIdx.x & 63;
    int row  = blockIdx.x * 4 + wave;            // [0, H*N)
    const float* w = emb + (size_t)row * DHD;
    float4 v = *(const float4*)(w + lane * 4);   // 64 lanes * 4 = 256 = DH
    float s = v.x * v.x + v.y * v.y + v.z * v.z + v.w * v.w;
    for (int off = 32; off; off >>= 1) s += __shfl_down(s, off);
    if (lane == 0) wsq[row] = s;
}

// ---------------------------------------------------------------------------
// logits[i][j] = 2*sum_k X[i][k]*W[j][k] - wsq[j] (+ sum_k P[i][k]*T[j][k])
// Tile 64x64, BK=16, 256 threads, 4x4 micro-tile.
// ---------------------------------------------------------------------------
template <int HASPREV>
__global__ __launch_bounds__(256) void k_logits(const float* __restrict__ X,
                                                const float* __restrict__ W,
                                                const float* __restrict__ wsq,
                                                const float* __restrict__ P,
                                                const float* __restrict__ T,
                                                float* __restrict__ out) {
    __shared__ float As[16][PAD];
    __shared__ float Bs[16][PAD];
    const int t  = threadIdx.x;
    const int tx = t & 15, ty = t >> 4;
    const int j0 = blockIdx.x * 64;   // N tile
    const int i0 = blockIdx.y * 64;   // B tile
    const int lr = t >> 2;            // 0..63
    const int lk = (t & 3) * 4;       // 0,4,8,12
    const int XLD = HH * DHD;

    float acc[4][4] = {};

    // phase 1: 2 * X . W^T  (K = DH)
    for (int k0 = 0; k0 < DHD; k0 += 16) {
        float4 av = *(const float4*)(X + (size_t)(i0 + lr) * XLD + k0 + lk);
        float4 bv = *(const float4*)(W + (size_t)(j0 + lr) * DHD + k0 + lk);
        As[lk + 0][lr] = 2.f * av.x; As[lk + 1][lr] = 2.f * av.y;
        As[lk + 2][lr] = 2.f * av.z; As[lk + 3][lr] = 2.f * av.w;
        Bs[lk + 0][lr] = bv.x; Bs[lk + 1][lr] = bv.y;
        Bs[lk + 2][lr] = bv.z; Bs[lk + 3][lr] = bv.w;
        __syncthreads();
#pragma unroll
        for (int kk = 0; kk < 16; kk++) {
            float4 a = *(const float4*)&As[kk][ty * 4];
            float4 b = *(const float4*)&Bs[kk][tx * 4];
            float av4[4] = {a.x, a.y, a.z, a.w};
            float bv4[4] = {b.x, b.y, b.z, b.w};
#pragma unroll
            for (int u = 0; u < 4; u++)
#pragma unroll
                for (int v = 0; v < 4; v++) acc[u][v] += av4[u] * bv4[v];
        }
        __syncthreads();
    }

    // phase 2: + P . T^T  (K = N)
    if (HASPREV) {
        for (int k0 = 0; k0 < NN; k0 += 16) {
            float4 av = *(const float4*)(P + (size_t)(i0 + lr) * NN + k0 + lk);
            float4 bv = *(const float4*)(T + (size_t)(j0 + lr) * NN + k0 + lk);
            As[lk + 0][lr] = av.x; As[lk + 1][lr] = av.y;
            As[lk + 2][lr] = av.z; As[lk + 3][lr] = av.w;
            Bs[lk + 0][lr] = bv.x; Bs[lk + 1][lr] = bv.y;
            Bs[lk + 2][lr] = bv.z; Bs[lk + 3][lr] = bv.w;
            __syncthreads();
#pragma unroll
            for (int kk = 0; kk < 16; kk++) {
                float4 a = *(const float4*)&As[kk][ty * 4];
                float4 b = *(const float4*)&Bs[kk][tx * 4];
                float av4[4] = {a.x, a.y, a.z, a.w};
                float bv4[4] = {b.x, b.y, b.z, b.w};
#pragma unroll
                for (int u = 0; u < 4; u++)
#pragma unroll
                    for (int v = 0; v < 4; v++) acc[u][v] += av4[u] * bv4[v];
            }
            __syncthreads();
        }
    }

#pragma unroll
    for (int u = 0; u < 4; u++) {
        int i = i0 + ty * 4 + u;
#pragma unroll
        for (int v = 0; v < 4; v++) {
            int j = j0 + tx * 4 + v;
            out[(size_t)i * NN + j] = acc[u][v] - wsq[j];
        }
    }
}

// ---------------------------------------------------------------------------
// In-place row softmax over N=1024, argmax -> codes (as float). Block per row.
// ---------------------------------------------------------------------------
__global__ __launch_bounds__(256) void k_softmax(float* __restrict__ L,
                                                 float* __restrict__ codes,
                                                 int h) {
    __shared__ float smax[256];
    __shared__ int   sidx[256];
    const int i = blockIdx.x;
    const int t = threadIdx.x;
    float* row = L + (size_t)i * NN;

    float v[4];
    float m = -INFINITY;
    int   mi = 0;
#pragma unroll
    for (int q = 0; q < 4; q++) {
        int j = q * 256 + t;
        v[q] = row[j];
        if (v[q] > m) { m = v[q]; mi = j; }
    }
    smax[t] = m; sidx[t] = mi;
    __syncthreads();
    for (int s = 128; s; s >>= 1) {
        if (t < s) {
            float o = smax[t + s]; int oi = sidx[t + s];
            if (o > smax[t] || (o == smax[t] && oi < sidx[t])) { smax[t] = o; sidx[t] = oi; }
        }
        __syncthreads();
    }
    m = smax[0];
    int code = sidx[0];
    __syncthreads();

    float s = 0.f;
#pragma unroll
    for (int q = 0; q < 4; q++) { v[q] = expf(v[q] - m); s += v[q]; }
    smax[t] = s;
    __syncthreads();
    for (int ss = 128; ss; ss >>= 1) {
        if (t < ss) smax[t] += smax[t + ss];
        __syncthreads();
    }
    float inv = 1.0f / smax[0];
#pragma unroll
    for (int q = 0; q < 4; q++) row[q * 256 + t] = v[q] * inv;

    if (t == 0) codes[(size_t)i * HH + h] = (float)code;
}

// ---------------------------------------------------------------------------
// colsum[j] += sum over a 256-row slab of P[i][j]
// ---------------------------------------------------------------------------
__global__ __launch_bounds__(256) void k_colsum(const float* __restrict__ P,
                                                float* __restrict__ colsum) {
    int j  = blockIdx.x * 256 + threadIdx.x;
    int i0 = blockIdx.y * 256;
    float s = 0.f;
    for (int i = i0; i < i0 + 256; i++) s += P[(size_t)i * NN + j];
    atomicAdd(&colsum[j], s);
}

// ---------------------------------------------------------------------------
// csn[j] = (cs[j]+eps)/(n+N*eps)*n
// ---------------------------------------------------------------------------
__global__ __launch_bounds__(1024) void k_cs(const float* __restrict__ cluster_size,
                                             const float* __restrict__ colsum,
                                             float* __restrict__ csn, int h) {
    __shared__ float red[1024];
    int j = threadIdx.x;
    float cs = cluster_size[h * NN + j] * DECAY + OMD * colsum[j];
    red[j] = cs;
    __syncthreads();
    for (int s = 512; s; s >>= 1) {
        if (j < s) red[j] += red[j + s];
        __syncthreads();
    }
    float n = red[0];
    csn[j] = (cs + EPSV) / (n + NN * EPSV) * n;
}

// ---------------------------------------------------------------------------
// Split-K partial of dw[j][k] = sum_i P[i][j]*X[i][k].
// grid (DHD/64, NN/64, 16); each z-slab covers 256 rows of B.
// ---------------------------------------------------------------------------
__global__ __launch_bounds__(256) void k_dw(const float* __restrict__ P,
                                            const float* __restrict__ X,
                                            float* __restrict__ partial) {
    __shared__ float As[16][PAD];   // As[i_k][j]
    __shared__ float Bs[16][PAD];   // Bs[i_k][k]
    const int t    = threadIdx.x;
    const int tx   = t & 15, ty = t >> 4;
    const int k0c  = blockIdx.x * 64;   // DH tile
    const int j0   = blockIdx.y * 64;   // N tile
    const int ibeg = blockIdx.z * 256;  // K slab
    const int lkk  = t >> 4;            // 0..15
    const int lm4  = (t & 15) * 4;      // 0..60
    const int XLD  = HH * DHD;

    float acc[4][4] = {};
    for (int i0 = ibeg; i0 < ibeg + 256; i0 += 16) {
        float4 av = *(const float4*)(P + (size_t)(i0 + lkk) * NN + j0 + lm4);
        float4 bv = *(const float4*)(X + (size_t)(i0 + lkk) * XLD + k0c + lm4);
        *(float4*)&As[lkk][lm4] = av;
        *(float4*)&Bs[lkk][lm4] = bv;
        __syncthreads();
#pragma unroll
        for (int kk = 0; kk < 16; kk++) {
            float4 a = *(const float4*)&As[kk][ty * 4];
            float4 b = *(const float4*)&Bs[kk][tx * 4];
            float av4[4] = {a.x, a.y, a.z, a.w};
            float bv4[4] = {b.x, b.y, b.z, b.w};
#pragma unroll
            for (int u = 0; u < 4; u++)
#pragma unroll
                for (int v = 0; v < 4; v++) acc[u][v] += av4[u] * bv4[v];
        }
        __syncthreads();
    }
#pragma unroll
    for (int u = 0; u < 4; u++) {
        int j = j0 + ty * 4 + u;
#pragma unroll
        for (int v = 0; v < 4; v++) {
            int k = k0c + tx * 4 + v;
            atomicAdd(&partial[(size_t)j * DHD + k], acc[u][v]);
        }
    }
}

// neww[j][k] = (ema[j][k]*DECAY + OMD*partial[j][k]) / csn[j]
__global__ __launch_bounds__(256) void k_neww_ep(const float* __restrict__ partial,
                                                 const float* __restrict__ ema,
                                                 const float* __restrict__ csn,
                                                 float* __restrict__ neww) {
    int idx = blockIdx.x * 256 + threadIdx.x;
    int j = idx >> 8;   // DHD = 256
    neww[idx] = (ema[idx] * DECAY + OMD * partial[idx]) / csn[j];
}

// ---------------------------------------------------------------------------
// Split-K partial of q[i][k] = sum_j P[i][j]*Wn[j][k].
// grid (DHD/64, BB/64, 4); each z-slab covers 256 of N.
// ---------------------------------------------------------------------------
__global__ __launch_bounds__(256) void k_quant(const float* __restrict__ P,
                                               const float* __restrict__ Wn,
                                               float* __restrict__ qacc) {
    __shared__ float As[16][PAD];   // As[j_k][i]
    __shared__ float Bs[16][PAD];   // Bs[j_k][k]
    const int t    = threadIdx.x;
    const int tx   = t & 15, ty = t >> 4;
    const int k0c  = blockIdx.x * 64;  // DH tile
    const int i0   = blockIdx.y * 64;  // B tile
    const int jbeg = blockIdx.z * 256; // K slab over N
    const int lr   = t >> 2, lk4 = (t & 3) * 4;   // A trans-load
    const int lkk  = t >> 4, ln4 = (t & 15) * 4;  // B direct-load

    float acc[4][4] = {};
    for (int j0 = jbeg; j0 < jbeg + 256; j0 += 16) {
        float4 av = *(const float4*)(P + (size_t)(i0 + lr) * NN + j0 + lk4);
        As[lk4 + 0][lr] = av.x; As[lk4 + 1][lr] = av.y;
        As[lk4 + 2][lr] = av.z; As[lk4 + 3][lr] = av.w;
        float4 bv = *(const float4*)(Wn + (size_t)(j0 + lkk) * DHD + k0c + ln4);
        *(float4*)&Bs[lkk][ln4] = bv;
        __syncthreads();
#pragma unroll
        for (int kk = 0; kk < 16; kk++) {
            float4 a = *(const float4*)&As[kk][ty * 4];
            float4 b = *(const float4*)&Bs[kk][tx * 4];
            float av4[4] = {a.x, a.y, a.z, a.w};
            float bv4[4] = {b.x, b.y, b.z, b.w};
#pragma unroll
            for (int u = 0; u < 4; u++)
#pragma unroll
                for (int v = 0; v < 4; v++) acc[u][v] += av4[u] * bv4[v];
        }
        __syncthreads();
    }
#pragma unroll
    for (int u = 0; u < 4; u++) {
        int i = i0 + ty * 4 + u;
#pragma unroll
        for (int v = 0; v < 4; v++) {
            int k = k0c + tx * 4 + v;
            atomicAdd(&qacc[(size_t)i * DHD + k], acc[u][v]);
        }
    }
}

// out[i][h*DH+k] = qacc[i][k]
__global__ __launch_bounds__(256) void k_quant_ep(const float* __restrict__ qacc,
                                                  float* __restrict__ outq, int h) {
    int idx = blockIdx.x * 256 + threadIdx.x;   // over BB*DHD
    int i = idx >> 8;
    int k = idx & 255;
    outq[(size_t)i * (HH * DHD) + h * DHD + k] = qacc[idx];
}

// ---------------------------------------------------------------------------
// loss[i] = 1.25 * mean_k (q[i][k] - x[i][k])^2   over H*DH = 1024
// ---------------------------------------------------------------------------
__global__ __launch_bounds__(256) void k_loss(const float* __restrict__ x,
                                              const float* __restrict__ q,
                                              float* __restrict__ loss) {
    __shared__ float red[256];
    const int i = blockIdx.x, t = threadIdx.x;
    const float* xr = x + (size_t)i * 1024;
    const float* qr = q + (size_t)i * 1024;
    float s = 0.f;
#pragma unroll
    for (int q4 = 0; q4 < 4; q4++) {
        int k = q4 * 256 + t;
        float d = qr[k] - xr[k];
        s += d * d;
    }
    red[t] = s;
    __syncthreads();
    for (int ss = 128; ss; ss >>= 1) {
        if (t < ss) red[t] += red[t + ss];
        __syncthreads();
    }
    if (t == 0) loss[i] = 1.25f * red[0] * (1.0f / 1024.0f);
}

// ---------------------------------------------------------------------------
extern "C" void kernel_launch(void* const* d_in, const int* in_sizes, int n_in,
                              void* d_out, int out_size, void* d_ws, size_t ws_size,
                              hipStream_t stream) {
    const float* inputs = (const float*)d_in[0];   // B x (H*DH)
    const float* emb    = (const float*)d_in[1];   // H x N x DH
    const float* ema    = (const float*)d_in[2];   // H x N x DH
    const float* csz    = (const float*)d_in[3];   // H x N
    const float* trans  = (const float*)d_in[4];   // H x N x N

    float* out   = (float*)d_out;
    float* loss  = out;                               // B
    float* quant = out + BB;                          // B*H*DH
    float* codes = out + BB + (size_t)BB * HH * DHD;  // B*H

    float* ws      = (float*)d_ws;
    float* P0      = ws;                           // B*N
    float* P1      = P0 + (size_t)BB * NN;         // B*N
    float* wsq     = P1 + (size_t)BB * NN;         // H*N
    float* colsum  = wsq + HH * NN;                // N
    float* csn     = colsum + NN;                  // N
    float* neww    = csn + NN;                     // N*DH
    float* partial = neww + (size_t)NN * DHD;      // N*DH
    float* qacc    = partial + (size_t)NN * DHD;   // B*DH

    k_wsq<<<HH * NN / 4, 256, 0, stream>>>(emb, wsq);

    float* Pprev = P1;
    float* Pcur  = P0;
    for (int h = 0; h < HH; h++) {
        const float* X = inputs + h * DHD;
        const float* W = emb + (size_t)h * NN * DHD;
        if (h == 0)
            k_logits<0><<<dim3(NN / 64, BB / 64), 256, 0, stream>>>(
                X, W, wsq + h * NN, nullptr, nullptr, Pcur);
        else
            k_logits<1><<<dim3(NN / 64, BB / 64), 256, 0, stream>>>(
                X, W, wsq + h * NN, Pprev, trans + (size_t)h * NN * NN, Pcur);

        k_softmax<<<BB, 256, 0, stream>>>(Pcur, codes, h);

        hipMemsetAsync(colsum, 0, NN * sizeof(float), stream);
        k_colsum<<<dim3(NN / 256, 16), 256, 0, stream>>>(Pcur, colsum);
        k_cs<<<1, NN, 0, stream>>>(csz, colsum, csn, h);

        hipMemsetAsync(partial, 0, (size_t)NN * DHD * sizeof(float), stream);
        k_dw<<<dim3(DHD / 64, NN / 64, 16), 256, 0, stream>>>(Pcur, X, partial);
        k_neww_ep<<<NN * DHD / 256, 256, 0, stream>>>(partial,
                                                      ema + (size_t)h * NN * DHD,
                                                      csn, neww);

        hipMemsetAsync(qacc, 0, (size_t)BB * DHD * sizeof(float), stream);
        k_quant<<<dim3(DHD / 64, BB / 64, 4), 256, 0, stream>>>(Pcur, neww, qacc);
        k_quant_ep<<<BB * DHD / 256, 256, 0, stream>>>(qacc, quant, h);

        float* tmp = Pprev; Pprev = Pcur; Pcur = tmp;
    }

    k_loss<<<BB, 256, 0, stream>>>(inputs, quant, loss);
}

// Round 4
// 678.768 us; speedup vs baseline: 3.6394x; 1.8977x over previous
//
#include <hip/hip_runtime.h>
#include <hip/hip_bf16.h>
#include <math.h>

#define BB 4096
#define HH 4
#define NN 1024
#define DHD 256
#define XLD 1024   // H*DH
#define DECAY 0.99f
#define OMD 0.01f
#define EPSV 1e-5f

typedef __attribute__((ext_vector_type(8))) short bf16x8;
typedef __attribute__((ext_vector_type(4))) float f32x4;
typedef unsigned short u16;

#define MFMA(a, b, c) __builtin_amdgcn_mfma_f32_16x16x32_bf16((a), (b), (c), 0, 0, 0)

static __device__ __forceinline__ u16 f2bf(float x) {
    union { __hip_bfloat16 b; u16 u; } c; c.b = __float2bfloat16(x); return c.u;
}
static __device__ __forceinline__ float bf2f(u16 u) {
    union { __hip_bfloat16 b; u16 u; } c; c.u = u; return __bfloat162float(c.b);
}
static __device__ __forceinline__ void split3(float x, u16& h, u16& m, u16& l) {
    h = f2bf(x);
    float r = x - bf2f(h);
    m = f2bf(r);
    float r2 = r - bf2f(m);
    l = f2bf(r2);
}

// ---------------------------------------------------------------------------
// prep X: Xh2/Xm2/Xl2 = 3-level split(2x) straight; XTh/XTl = 2-level split(x)
// transposed. grid (XLD/64, BB/64)
// ---------------------------------------------------------------------------
__global__ __launch_bounds__(256) void k_prep_x(const float* __restrict__ in,
        u16* __restrict__ xh2, u16* __restrict__ xm2, u16* __restrict__ xl2,
        u16* __restrict__ xth, u16* __restrict__ xtl) {
    __shared__ float T[64][68];
    const int t = threadIdx.x;
    const int c0 = blockIdx.x * 64, i0 = blockIdx.y * 64;
#pragma unroll
    for (int rep = 0; rep < 4; rep++) {
        int id = t + 256 * rep;
        int row = id >> 4, c4 = (id & 15) * 4;
        float4 v = *(const float4*)(in + (size_t)(i0 + row) * XLD + c0 + c4);
        *(float4*)&T[row][c4] = v;
        float xs[4] = {v.x, v.y, v.z, v.w};
        u16 h4[4], m4[4], l4[4];
#pragma unroll
        for (int e = 0; e < 4; e++) split3(2.f * xs[e], h4[e], m4[e], l4[e]);
        size_t o = (size_t)(i0 + row) * XLD + c0 + c4;
        *(ushort4*)(xh2 + o) = make_ushort4(h4[0], h4[1], h4[2], h4[3]);
        *(ushort4*)(xm2 + o) = make_ushort4(m4[0], m4[1], m4[2], m4[3]);
        *(ushort4*)(xl2 + o) = make_ushort4(l4[0], l4[1], l4[2], l4[3]);
    }
    __syncthreads();
    const int or_ = t >> 2, oc = (t & 3) * 16;
    bf16x8 h0, h1, l0, l1;
#pragma unroll
    for (int e = 0; e < 8; e++) {
        float x = T[oc + e][or_];
        u16 h = f2bf(x);
        h0[e] = (short)h; l0[e] = (short)f2bf(x - bf2f(h));
    }
#pragma unroll
    for (int e = 0; e < 8; e++) {
        float x = T[oc + 8 + e][or_];
        u16 h = f2bf(x);
        h1[e] = (short)h; l1[e] = (short)f2bf(x - bf2f(h));
    }
    size_t o = (size_t)(c0 + or_) * BB + i0 + oc;
    *(bf16x8*)(xth + o) = h0;
    *(bf16x8*)(xth + o + 8) = h1;
    *(bf16x8*)(xtl + o) = l0;
    *(bf16x8*)(xtl + o + 8) = l1;
}

// ---------------------------------------------------------------------------
// prep W: 3-level split elementwise (H*N*DH)
// ---------------------------------------------------------------------------
__global__ __launch_bounds__(256) void k_prep_w(const float* __restrict__ w,
        u16* __restrict__ wh, u16* __restrict__ wm, u16* __restrict__ wl) {
    size_t id = ((size_t)blockIdx.x * 256 + threadIdx.x) * 4;
    float4 v = *(const float4*)(w + id);
    float xs[4] = {v.x, v.y, v.z, v.w};
    u16 h4[4], m4[4], l4[4];
#pragma unroll
    for (int e = 0; e < 4; e++) split3(xs[e], h4[e], m4[e], l4[e]);
    *(ushort4*)(wh + id) = make_ushort4(h4[0], h4[1], h4[2], h4[3]);
    *(ushort4*)(wm + id) = make_ushort4(m4[0], m4[1], m4[2], m4[3]);
    *(ushort4*)(wl + id) = make_ushort4(l4[0], l4[1], l4[2], l4[3]);
}

// prep T: 2-level split (H*N*N)
__global__ __launch_bounds__(256) void k_prep_t(const float* __restrict__ w,
        u16* __restrict__ th, u16* __restrict__ tl) {
    size_t id = ((size_t)blockIdx.x * 256 + threadIdx.x) * 4;
    float4 v = *(const float4*)(w + id);
    float xs[4] = {v.x, v.y, v.z, v.w};
    u16 h4[4], l4[4];
#pragma unroll
    for (int e = 0; e < 4; e++) {
        u16 h = f2bf(xs[e]);
        h4[e] = h;
        l4[e] = f2bf(xs[e] - bf2f(h));
    }
    *(ushort4*)(th + id) = make_ushort4(h4[0], h4[1], h4[2], h4[3]);
    *(ushort4*)(tl + id) = make_ushort4(l4[0], l4[1], l4[2], l4[3]);
}

// ---------------------------------------------------------------------------
// wsq[row] = sum_k emb[row][k]^2  (fp32 exact)
// ---------------------------------------------------------------------------
__global__ __launch_bounds__(256) void k_wsq(const float* __restrict__ emb,
                                             float* __restrict__ wsq) {
    int wave = threadIdx.x >> 6;
    int lane = threadIdx.x & 63;
    int row  = blockIdx.x * 4 + wave;
    const float* w = emb + (size_t)row * DHD;
    float4 v = *(const float4*)(w + lane * 4);
    float s = v.x * v.x + v.y * v.y + v.z * v.z + v.w * v.w;
    for (int off = 32; off; off >>= 1) s += __shfl_down(s, off);
    if (lane == 0) wsq[row] = s;
}

// ---------------------------------------------------------------------------
// MFMA logits, high precision:
//  phase 1: 3-level split of (2x) and w, 6 terms; dominant h*H term goes to a
//           fresh accumulator per K-block, merged via VALU add (keeps MFMA
//           internal partials small). Small terms chain in acc2.
//  phase 2: 2-level split of P and T, 3 terms, chained into acc2 (small mag).
// TILE 128(M=i) x 64(N=j), BK=32. grid (NN/64, BB/128).
// ---------------------------------------------------------------------------
template <int HASPREV>
__global__ __launch_bounds__(256) void k_logits_mfma(
        const u16* __restrict__ Xh, const u16* __restrict__ Xm, const u16* __restrict__ Xl,
        const u16* __restrict__ Wh, const u16* __restrict__ Wm, const u16* __restrict__ Wl,
        const float* __restrict__ wsq,
        const u16* __restrict__ Ph, const u16* __restrict__ Pl,
        const u16* __restrict__ Th, const u16* __restrict__ Tl,
        float* __restrict__ L) {
    __shared__ u16 Ah[128 * 40], Am[128 * 40], Al[128 * 40];
    __shared__ u16 Bh[64 * 40], Bm[64 * 40], Bl[64 * 40];
    const int t = threadIdx.x;
    const int lane = t & 63, wid = t >> 6;
    const int wmi = wid >> 1, wn = wid & 1;
    const int q = lane >> 4, mr = lane & 15;
    const int j0 = blockIdx.x * 64, i0 = blockIdx.y * 128;
    const int ar = t >> 2, ac = (t & 3) * 8;

    f32x4 zero = {0.f, 0.f, 0.f, 0.f};
    f32x4 s[4][2], acc2[4][2];
#pragma unroll
    for (int mt = 0; mt < 4; mt++)
#pragma unroll
        for (int nt = 0; nt < 2; nt++) { s[mt][nt] = zero; acc2[mt][nt] = zero; }

    // ---- phase 1: split(2x) . split(w), K = DHD ----
    for (int kb = 0; kb < DHD; kb += 32) {
        bf16x8 a0h = *(const bf16x8*)(Xh + (size_t)(i0 + ar) * XLD + kb + ac);
        bf16x8 a1h = *(const bf16x8*)(Xh + (size_t)(i0 + ar + 64) * XLD + kb + ac);
        bf16x8 a0m = *(const bf16x8*)(Xm + (size_t)(i0 + ar) * XLD + kb + ac);
        bf16x8 a1m = *(const bf16x8*)(Xm + (size_t)(i0 + ar + 64) * XLD + kb + ac);
        bf16x8 a0l = *(const bf16x8*)(Xl + (size_t)(i0 + ar) * XLD + kb + ac);
        bf16x8 a1l = *(const bf16x8*)(Xl + (size_t)(i0 + ar + 64) * XLD + kb + ac);
        bf16x8 b0h = *(const bf16x8*)(Wh + (size_t)(j0 + ar) * DHD + kb + ac);
        bf16x8 b0m = *(const bf16x8*)(Wm + (size_t)(j0 + ar) * DHD + kb + ac);
        bf16x8 b0l = *(const bf16x8*)(Wl + (size_t)(j0 + ar) * DHD + kb + ac);
        __syncthreads();
        *(bf16x8*)&Ah[ar * 40 + ac] = a0h;
        *(bf16x8*)&Ah[(ar + 64) * 40 + ac] = a1h;
        *(bf16x8*)&Am[ar * 40 + ac] = a0m;
        *(bf16x8*)&Am[(ar + 64) * 40 + ac] = a1m;
        *(bf16x8*)&Al[ar * 40 + ac] = a0l;
        *(bf16x8*)&Al[(ar + 64) * 40 + ac] = a1l;
        *(bf16x8*)&Bh[ar * 40 + ac] = b0h;
        *(bf16x8*)&Bm[ar * 40 + ac] = b0m;
        *(bf16x8*)&Bl[ar * 40 + ac] = b0l;
        __syncthreads();
        bf16x8 afh[4], afm[4], afl[4], bfh[2], bfm[2], bfl[2];
#pragma unroll
        for (int mt = 0; mt < 4; mt++) {
            int row = (wmi * 64 + mt * 16 + mr) * 40 + q * 8;
            afh[mt] = *(const bf16x8*)&Ah[row];
            afm[mt] = *(const bf16x8*)&Am[row];
            afl[mt] = *(const bf16x8*)&Al[row];
        }
#pragma unroll
        for (int nt = 0; nt < 2; nt++) {
            int row = (wn * 32 + nt * 16 + mr) * 40 + q * 8;
            bfh[nt] = *(const bf16x8*)&Bh[row];
            bfm[nt] = *(const bf16x8*)&Bm[row];
            bfl[nt] = *(const bf16x8*)&Bl[row];
        }
#pragma unroll
        for (int mt = 0; mt < 4; mt++)
#pragma unroll
            for (int nt = 0; nt < 2; nt++) {
                f32x4 fresh = MFMA(afh[mt], bfh[nt], zero);   // dominant term
                s[mt][nt] += fresh;                           // VALU merge
                acc2[mt][nt] = MFMA(afh[mt], bfm[nt], acc2[mt][nt]);
                acc2[mt][nt] = MFMA(afm[mt], bfh[nt], acc2[mt][nt]);
                acc2[mt][nt] = MFMA(afh[mt], bfl[nt], acc2[mt][nt]);
                acc2[mt][nt] = MFMA(afm[mt], bfm[nt], acc2[mt][nt]);
                acc2[mt][nt] = MFMA(afl[mt], bfh[nt], acc2[mt][nt]);
            }
    }

    // ---- phase 2: split(P) . split(T)^T, K = NN, into small accumulator ----
    if (HASPREV) {
        for (int kb = 0; kb < NN; kb += 32) {
            bf16x8 a0h = *(const bf16x8*)(Ph + (size_t)(i0 + ar) * NN + kb + ac);
            bf16x8 a1h = *(const bf16x8*)(Ph + (size_t)(i0 + ar + 64) * NN + kb + ac);
            bf16x8 a0l = *(const bf16x8*)(Pl + (size_t)(i0 + ar) * NN + kb + ac);
            bf16x8 a1l = *(const bf16x8*)(Pl + (size_t)(i0 + ar + 64) * NN + kb + ac);
            bf16x8 b0h = *(const bf16x8*)(Th + (size_t)(j0 + ar) * NN + kb + ac);
            bf16x8 b0l = *(const bf16x8*)(Tl + (size_t)(j0 + ar) * NN + kb + ac);
            __syncthreads();
            *(bf16x8*)&Ah[ar * 40 + ac] = a0h;
            *(bf16x8*)&Ah[(ar + 64) * 40 + ac] = a1h;
            *(bf16x8*)&Al[ar * 40 + ac] = a0l;
            *(bf16x8*)&Al[(ar + 64) * 40 + ac] = a1l;
            *(bf16x8*)&Bh[ar * 40 + ac] = b0h;
            *(bf16x8*)&Bl[ar * 40 + ac] = b0l;
            __syncthreads();
            bf16x8 afh[4], afl[4], bfh[2], bfl[2];
#pragma unroll
            for (int mt = 0; mt < 4; mt++) {
                int row = (wmi * 64 + mt * 16 + mr) * 40 + q * 8;
                afh[mt] = *(const bf16x8*)&Ah[row];
                afl[mt] = *(const bf16x8*)&Al[row];
            }
#pragma unroll
            for (int nt = 0; nt < 2; nt++) {
                int row = (wn * 32 + nt * 16 + mr) * 40 + q * 8;
                bfh[nt] = *(const bf16x8*)&Bh[row];
                bfl[nt] = *(const bf16x8*)&Bl[row];
            }
#pragma unroll
            for (int mt = 0; mt < 4; mt++)
#pragma unroll
                for (int nt = 0; nt < 2; nt++) {
                    acc2[mt][nt] = MFMA(afh[mt], bfh[nt], acc2[mt][nt]);
                    acc2[mt][nt] = MFMA(afh[mt], bfl[nt], acc2[mt][nt]);
                    acc2[mt][nt] = MFMA(afl[mt], bfh[nt], acc2[mt][nt]);
                }
        }
    }

    float wq[2];
#pragma unroll
    for (int nt = 0; nt < 2; nt++) wq[nt] = wsq[j0 + wn * 32 + nt * 16 + mr];
#pragma unroll
    for (int mt = 0; mt < 4; mt++)
#pragma unroll
        for (int nt = 0; nt < 2; nt++)
#pragma unroll
            for (int r = 0; r < 4; r++) {
                int gi = i0 + wmi * 64 + mt * 16 + q * 4 + r;
                int gj = j0 + wn * 32 + nt * 16 + mr;
                L[(size_t)gi * NN + gj] = (s[mt][nt][r] + acc2[mt][nt][r]) - wq[nt];
            }
}

// ---------------------------------------------------------------------------
// softmax row of N=1024, argmax -> codes, writes split-bf16 probs
// ---------------------------------------------------------------------------
__global__ __launch_bounds__(256) void k_softmax(const float* __restrict__ L,
                                                 u16* __restrict__ Ph,
                                                 u16* __restrict__ Pl,
                                                 float* __restrict__ codes,
                                                 int h) {
    __shared__ float smax[256];
    __shared__ int   sidx[256];
    const int i = blockIdx.x;
    const int t = threadIdx.x;
    const float* row = L + (size_t)i * NN;

    float v[4];
    float m = -INFINITY;
    int   mi = 0;
#pragma unroll
    for (int q4 = 0; q4 < 4; q4++) {
        int j = q4 * 256 + t;
        v[q4] = row[j];
        if (v[q4] > m) { m = v[q4]; mi = j; }
    }
    smax[t] = m; sidx[t] = mi;
    __syncthreads();
    for (int s = 128; s; s >>= 1) {
        if (t < s) {
            float o = smax[t + s]; int oi = sidx[t + s];
            if (o > smax[t] || (o == smax[t] && oi < sidx[t])) { smax[t] = o; sidx[t] = oi; }
        }
        __syncthreads();
    }
    m = smax[0];
    int code = sidx[0];
    __syncthreads();

    float s = 0.f;
#pragma unroll
    for (int q4 = 0; q4 < 4; q4++) { v[q4] = expf(v[q4] - m); s += v[q4]; }
    smax[t] = s;
    __syncthreads();
    for (int ss = 128; ss; ss >>= 1) {
        if (t < ss) smax[t] += smax[t + ss];
        __syncthreads();
    }
    float inv = 1.0f / smax[0];
#pragma unroll
    for (int q4 = 0; q4 < 4; q4++) {
        float pv = v[q4] * inv;
        u16 hb = f2bf(pv);
        Ph[(size_t)i * NN + q4 * 256 + t] = hb;
        Pl[(size_t)i * NN + q4 * 256 + t] = f2bf(pv - bf2f(hb));
    }
    if (t == 0) codes[(size_t)i * HH + h] = (float)code;
}

// ---------------------------------------------------------------------------
// transpose Phi/Plo (B x N) -> PThi/PTlo (N x B). grid (NN/64, BB/64)
// ---------------------------------------------------------------------------
__global__ __launch_bounds__(256) void k_transposeP(const u16* __restrict__ Ph,
        const u16* __restrict__ Pl, u16* __restrict__ PTh, u16* __restrict__ PTl) {
    __shared__ u16 U[64][72];
    const int t = threadIdx.x;
    const int j0 = blockIdx.x * 64, i0 = blockIdx.y * 64;
    for (int pass = 0; pass < 2; pass++) {
        const u16* src = pass ? Pl : Ph;
        u16* dst = pass ? PTl : PTh;
        if (pass) __syncthreads();
#pragma unroll
        for (int rep = 0; rep < 2; rep++) {
            int id = t + 256 * rep;
            int row = id >> 3, c8 = (id & 7) * 8;
            *(bf16x8*)&U[row][c8] = *(const bf16x8*)(src + (size_t)(i0 + row) * NN + j0 + c8);
        }
        __syncthreads();
        int or_ = t >> 2, oc = (t & 3) * 16;
        bf16x8 v0, v1;
#pragma unroll
        for (int e = 0; e < 8; e++) v0[e] = (short)U[oc + e][or_];
#pragma unroll
        for (int e = 0; e < 8; e++) v1[e] = (short)U[oc + 8 + e][or_];
        size_t o = (size_t)(j0 + or_) * BB + i0 + oc;
        *(bf16x8*)(dst + o) = v0;
        *(bf16x8*)(dst + o + 8) = v1;
    }
}

// ---------------------------------------------------------------------------
// colsum[j] += slab sum of (Phi+Plo)
// ---------------------------------------------------------------------------
__global__ __launch_bounds__(256) void k_colsum(const u16* __restrict__ Ph,
                                                const u16* __restrict__ Pl,
                                                float* __restrict__ colsum) {
    int j  = blockIdx.x * 256 + threadIdx.x;
    int i0 = blockIdx.y * 256;
    float s = 0.f;
    for (int i = i0; i < i0 + 256; i++)
        s += bf2f(Ph[(size_t)i * NN + j]) + bf2f(Pl[(size_t)i * NN + j]);
    atomicAdd(&colsum[j], s);
}

// ---------------------------------------------------------------------------
// csn[j] = (cs[j]+eps)/(n+N*eps)*n
// ---------------------------------------------------------------------------
__global__ __launch_bounds__(1024) void k_cs(const float* __restrict__ cluster_size,
                                             const float* __restrict__ colsum,
                                             float* __restrict__ csn, int h) {
    __shared__ float red[1024];
    int j = threadIdx.x;
    float cs = cluster_size[h * NN + j] * DECAY + OMD * colsum[j];
    red[j] = cs;
    __syncthreads();
    for (int s = 512; s; s >>= 1) {
        if (j < s) red[j] += red[j + s];
        __syncthreads();
    }
    float n = red[0];
    csn[j] = (cs + EPSV) / (n + NN * EPSV) * n;
}

// ---------------------------------------------------------------------------
// dw partial: dw[j][kd] = sum_i P[i][j]*X[i][kd] via PT (A) x XT (B), split x split.
// TILE 128(M=j) x 64(N=kd). grid (DHD/64, NN/128, 16 i-slabs of 256)
// ---------------------------------------------------------------------------
__global__ __launch_bounds__(256) void k_dw(
        const u16* __restrict__ PTh, const u16* __restrict__ PTl,  // [N][B]
        const u16* __restrict__ XTh, const u16* __restrict__ XTl,  // head [DH][B]
        float* __restrict__ partial) {                             // [N][DH]
    __shared__ u16 Ah[128 * 40], Al[128 * 40], Bh[64 * 40], Bl[64 * 40];
    const int t = threadIdx.x;
    const int lane = t & 63, wid = t >> 6;
    const int wmi = wid >> 1, wn = wid & 1;
    const int q = lane >> 4, mr = lane & 15;
    const int kd0 = blockIdx.x * 64, j0 = blockIdx.y * 128;
    const int ibeg = blockIdx.z * 256;
    const int ar = t >> 2, ac = (t & 3) * 8;

    f32x4 zero = {0.f, 0.f, 0.f, 0.f};
    f32x4 acc[4][2];
#pragma unroll
    for (int mt = 0; mt < 4; mt++)
#pragma unroll
        for (int nt = 0; nt < 2; nt++) acc[mt][nt] = zero;

    for (int ib = ibeg; ib < ibeg + 256; ib += 32) {
        bf16x8 a0h = *(const bf16x8*)(PTh + (size_t)(j0 + ar) * BB + ib + ac);
        bf16x8 a1h = *(const bf16x8*)(PTh + (size_t)(j0 + ar + 64) * BB + ib + ac);
        bf16x8 a0l = *(const bf16x8*)(PTl + (size_t)(j0 + ar) * BB + ib + ac);
        bf16x8 a1l = *(const bf16x8*)(PTl + (size_t)(j0 + ar + 64) * BB + ib + ac);
        bf16x8 b0h = *(const bf16x8*)(XTh + (size_t)(kd0 + ar) * BB + ib + ac);
        bf16x8 b0l = *(const bf16x8*)(XTl + (size_t)(kd0 + ar) * BB + ib + ac);
        __syncthreads();
        *(bf16x8*)&Ah[ar * 40 + ac] = a0h;
        *(bf16x8*)&Ah[(ar + 64) * 40 + ac] = a1h;
        *(bf16x8*)&Al[ar * 40 + ac] = a0l;
        *(bf16x8*)&Al[(ar + 64) * 40 + ac] = a1l;
        *(bf16x8*)&Bh[ar * 40 + ac] = b0h;
        *(bf16x8*)&Bl[ar * 40 + ac] = b0l;
        __syncthreads();
        bf16x8 afh[4], afl[4], bfh[2], bfl[2];
#pragma unroll
        for (int mt = 0; mt < 4; mt++) {
            afh[mt] = *(const bf16x8*)&Ah[(wmi * 64 + mt * 16 + mr) * 40 + q * 8];
            afl[mt] = *(const bf16x8*)&Al[(wmi * 64 + mt * 16 + mr) * 40 + q * 8];
        }
#pragma unroll
        for (int nt = 0; nt < 2; nt++) {
            bfh[nt] = *(const bf16x8*)&Bh[(wn * 32 + nt * 16 + mr) * 40 + q * 8];
            bfl[nt] = *(const bf16x8*)&Bl[(wn * 32 + nt * 16 + mr) * 40 + q * 8];
        }
#pragma unroll
        for (int mt = 0; mt < 4; mt++)
#pragma unroll
            for (int nt = 0; nt < 2; nt++) {
                acc[mt][nt] = MFMA(afh[mt], bfh[nt], acc[mt][nt]);
                acc[mt][nt] = MFMA(afh[mt], bfl[nt], acc[mt][nt]);
                acc[mt][nt] = MFMA(afl[mt], bfh[nt], acc[mt][nt]);
            }
    }
#pragma unroll
    for (int mt = 0; mt < 4; mt++)
#pragma unroll
        for (int nt = 0; nt < 2; nt++)
#pragma unroll
            for (int r = 0; r < 4; r++) {
                int gj = j0 + wmi * 64 + mt * 16 + q * 4 + r;
                int gk = kd0 + wn * 32 + nt * 16 + mr;
                atomicAdd(&partial[(size_t)gj * DHD + gk], acc[mt][nt][r]);
            }
}

// ---------------------------------------------------------------------------
// neww epilogue + transpose: NWT[kd][j] = split((ema*DECAY + OMD*partial)/csn[j])
// grid (NN/64, DHD/64)
// ---------------------------------------------------------------------------
__global__ __launch_bounds__(256) void k_neww_ep(const float* __restrict__ partial,
        const float* __restrict__ ema, const float* __restrict__ csn,
        u16* __restrict__ NWh, u16* __restrict__ NWl) {
    __shared__ float T[64][68];
    const int t = threadIdx.x;
    const int j0 = blockIdx.x * 64, kd0 = blockIdx.y * 64;
#pragma unroll
    for (int rep = 0; rep < 4; rep++) {
        int id = t + 256 * rep;
        int jr = id >> 4, c4 = (id & 15) * 4;
        float4 pp = *(const float4*)(partial + (size_t)(j0 + jr) * DHD + kd0 + c4);
        float4 ee = *(const float4*)(ema + (size_t)(j0 + jr) * DHD + kd0 + c4);
        float ic = 1.0f / csn[j0 + jr];
        float4 v;
        v.x = (ee.x * DECAY + OMD * pp.x) * ic;
        v.y = (ee.y * DECAY + OMD * pp.y) * ic;
        v.z = (ee.z * DECAY + OMD * pp.z) * ic;
        v.w = (ee.w * DECAY + OMD * pp.w) * ic;
        *(float4*)&T[jr][c4] = v;
    }
    __syncthreads();
    const int or_ = t >> 2, oc = (t & 3) * 16;
    bf16x8 h0, h1, l0, l1;
#pragma unroll
    for (int e = 0; e < 8; e++) {
        float x = T[oc + e][or_];
        u16 h = f2bf(x);
        h0[e] = (short)h; l0[e] = (short)f2bf(x - bf2f(h));
    }
#pragma unroll
    for (int e = 0; e < 8; e++) {
        float x = T[oc + 8 + e][or_];
        u16 h = f2bf(x);
        h1[e] = (short)h; l1[e] = (short)f2bf(x - bf2f(h));
    }
    size_t o = (size_t)(kd0 + or_) * NN + j0 + oc;
    *(bf16x8*)(NWh + o) = h0;
    *(bf16x8*)(NWh + o + 8) = h1;
    *(bf16x8*)(NWl + o) = l0;
    *(bf16x8*)(NWl + o + 8) = l1;
}

// ---------------------------------------------------------------------------
// quant: q[i][kd] += sum_j P[i][j]*NW[j][kd] via P (A) x NWT (B), split x split.
// TILE 128(M=i) x 64(N=kd). grid (DHD/64, BB/128, 4 j-slabs of 256).
// ---------------------------------------------------------------------------
__global__ __launch_bounds__(256) void k_quant(
        const u16* __restrict__ Ph, const u16* __restrict__ Pl,    // [B][N]
        const u16* __restrict__ NWh, const u16* __restrict__ NWl,  // [DH][N]
        float* __restrict__ outq, int h) {                         // [B][XLD]
    __shared__ u16 Ah[128 * 40], Al[128 * 40], Bh[64 * 40], Bl[64 * 40];
    const int t = threadIdx.x;
    const int lane = t & 63, wid = t >> 6;
    const int wmi = wid >> 1, wn = wid & 1;
    const int q = lane >> 4, mr = lane & 15;
    const int kd0 = blockIdx.x * 64, i0 = blockIdx.y * 128;
    const int jbeg = blockIdx.z * 256;
    const int ar = t >> 2, ac = (t & 3) * 8;

    f32x4 zero = {0.f, 0.f, 0.f, 0.f};
    f32x4 acc[4][2];
#pragma unroll
    for (int mt = 0; mt < 4; mt++)
#pragma unroll
        for (int nt = 0; nt < 2; nt++) acc[mt][nt] = zero;

    for (int jb = jbeg; jb < jbeg + 256; jb += 32) {
        bf16x8 a0h = *(const bf16x8*)(Ph + (size_t)(i0 + ar) * NN + jb + ac);
        bf16x8 a1h = *(const bf16x8*)(Ph + (size_t)(i0 + ar + 64) * NN + jb + ac);
        bf16x8 a0l = *(const bf16x8*)(Pl + (size_t)(i0 + ar) * NN + jb + ac);
        bf16x8 a1l = *(const bf16x8*)(Pl + (size_t)(i0 + ar + 64) * NN + jb + ac);
        bf16x8 b0h = *(const bf16x8*)(NWh + (size_t)(kd0 + ar) * NN + jb + ac);
        bf16x8 b0l = *(const bf16x8*)(NWl + (size_t)(kd0 + ar) * NN + jb + ac);
        __syncthreads();
        *(bf16x8*)&Ah[ar * 40 + ac] = a0h;
        *(bf16x8*)&Ah[(ar + 64) * 40 + ac] = a1h;
        *(bf16x8*)&Al[ar * 40 + ac] = a0l;
        *(bf16x8*)&Al[(ar + 64) * 40 + ac] = a1l;
        *(bf16x8*)&Bh[ar * 40 + ac] = b0h;
        *(bf16x8*)&Bl[ar * 40 + ac] = b0l;
        __syncthreads();
        bf16x8 afh[4], afl[4], bfh[2], bfl[2];
#pragma unroll
        for (int mt = 0; mt < 4; mt++) {
            afh[mt] = *(const bf16x8*)&Ah[(wmi * 64 + mt * 16 + mr) * 40 + q * 8];
            afl[mt] = *(const bf16x8*)&Al[(wmi * 64 + mt * 16 + mr) * 40 + q * 8];
        }
#pragma unroll
        for (int nt = 0; nt < 2; nt++) {
            bfh[nt] = *(const bf16x8*)&Bh[(wn * 32 + nt * 16 + mr) * 40 + q * 8];
            bfl[nt] = *(const bf16x8*)&Bl[(wn * 32 + nt * 16 + mr) * 40 + q * 8];
        }
#pragma unroll
        for (int mt = 0; mt < 4; mt++)
#pragma unroll
            for (int nt = 0; nt < 2; nt++) {
                acc[mt][nt] = MFMA(afh[mt], bfh[nt], acc[mt][nt]);
                acc[mt][nt] = MFMA(afh[mt], bfl[nt], acc[mt][nt]);
                acc[mt][nt] = MFMA(afl[mt], bfh[nt], acc[mt][nt]);
            }
    }
#pragma unroll
    for (int mt = 0; mt < 4; mt++)
#pragma unroll
        for (int nt = 0; nt < 2; nt++)
#pragma unroll
            for (int r = 0; r < 4; r++) {
                int gi = i0 + wmi * 64 + mt * 16 + q * 4 + r;
                int gk = kd0 + wn * 32 + nt * 16 + mr;
                atomicAdd(&outq[(size_t)gi * XLD + h * DHD + gk], acc[mt][nt][r]);
            }
}

// ---------------------------------------------------------------------------
// loss[i] = 1.25 * mean_k (q[i][k] - x[i][k])^2
// ---------------------------------------------------------------------------
__global__ __launch_bounds__(256) void k_loss(const float* __restrict__ x,
                                              const float* __restrict__ qv,
                                              float* __restrict__ loss) {
    __shared__ float red[256];
    const int i = blockIdx.x, t = threadIdx.x;
    const float* xr = x + (size_t)i * XLD;
    const float* qr = qv + (size_t)i * XLD;
    float s = 0.f;
#pragma unroll
    for (int q4 = 0; q4 < 4; q4++) {
        int k = q4 * 256 + t;
        float d = qr[k] - xr[k];
        s += d * d;
    }
    red[t] = s;
    __syncthreads();
    for (int ss = 128; ss; ss >>= 1) {
        if (t < ss) red[t] += red[t + ss];
        __syncthreads();
    }
    if (t == 0) loss[i] = 1.25f * red[0] * (1.0f / 1024.0f);
}

// ---------------------------------------------------------------------------
extern "C" void kernel_launch(void* const* d_in, const int* in_sizes, int n_in,
                              void* d_out, int out_size, void* d_ws, size_t ws_size,
                              hipStream_t stream) {
    const float* inputs = (const float*)d_in[0];
    const float* emb    = (const float*)d_in[1];
    const float* ema    = (const float*)d_in[2];
    const float* csz    = (const float*)d_in[3];
    const float* trans  = (const float*)d_in[4];

    float* out   = (float*)d_out;
    float* loss  = out;
    float* quant = out + BB;
    float* codes = out + BB + (size_t)BB * XLD;

    char* p = (char*)d_ws;
    float* L = (float*)p; p += (size_t)BB * NN * 4;   // 16MB; PT aliased here
    u16* PTh = (u16*)L;
    u16* PTl = PTh + (size_t)BB * NN;
    u16* Ph  = (u16*)p; p += (size_t)BB * NN * 2;
    u16* Pl  = (u16*)p; p += (size_t)BB * NN * 2;
    u16* Xh2 = (u16*)p; p += (size_t)BB * XLD * 2;
    u16* Xm2 = (u16*)p; p += (size_t)BB * XLD * 2;
    u16* Xl2 = (u16*)p; p += (size_t)BB * XLD * 2;
    u16* XTh = (u16*)p; p += (size_t)XLD * BB * 2;
    u16* XTl = (u16*)p; p += (size_t)XLD * BB * 2;
    u16* Wh  = (u16*)p; p += (size_t)HH * NN * DHD * 2;
    u16* Wm  = (u16*)p; p += (size_t)HH * NN * DHD * 2;
    u16* Wl  = (u16*)p; p += (size_t)HH * NN * DHD * 2;
    u16* Th  = (u16*)p; p += (size_t)HH * NN * NN * 2;
    u16* Tl  = (u16*)p; p += (size_t)HH * NN * NN * 2;
    u16* NWh = (u16*)p; p += (size_t)DHD * NN * 2;
    u16* NWl = (u16*)p; p += (size_t)DHD * NN * 2;
    float* wsq    = (float*)p; p += (size_t)HH * NN * 4;
    float* colsum = (float*)p; p += NN * 4;
    float* csn    = (float*)p; p += NN * 4;
    float* partial = (float*)p; p += (size_t)NN * DHD * 4;

    k_prep_x<<<dim3(XLD / 64, BB / 64), 256, 0, stream>>>(inputs, Xh2, Xm2, Xl2, XTh, XTl);
    k_prep_w<<<HH * NN * DHD / 1024, 256, 0, stream>>>(emb, Wh, Wm, Wl);
    k_prep_t<<<HH * NN * NN / 1024, 256, 0, stream>>>(trans, Th, Tl);
    k_wsq<<<HH * NN / 4, 256, 0, stream>>>(emb, wsq);
    hipMemsetAsync(quant, 0, (size_t)BB * XLD * 4, stream);

    for (int h = 0; h < HH; h++) {
        const u16* Xhh = Xh2 + h * DHD;
        const u16* Xmh = Xm2 + h * DHD;
        const u16* Xlh = Xl2 + h * DHD;
        const u16* Whh = Wh + (size_t)h * NN * DHD;
        const u16* Wmh = Wm + (size_t)h * NN * DHD;
        const u16* Wlh = Wl + (size_t)h * NN * DHD;
        if (h == 0)
            k_logits_mfma<0><<<dim3(NN / 64, BB / 128), 256, 0, stream>>>(
                Xhh, Xmh, Xlh, Whh, Wmh, Wlh, wsq + h * NN,
                nullptr, nullptr, nullptr, nullptr, L);
        else
            k_logits_mfma<1><<<dim3(NN / 64, BB / 128), 256, 0, stream>>>(
                Xhh, Xmh, Xlh, Whh, Wmh, Wlh, wsq + h * NN,
                Ph, Pl, Th + (size_t)h * NN * NN, Tl + (size_t)h * NN * NN, L);

        k_softmax<<<BB, 256, 0, stream>>>(L, Ph, Pl, codes, h);
        k_transposeP<<<dim3(NN / 64, BB / 64), 256, 0, stream>>>(Ph, Pl, PTh, PTl);

        hipMemsetAsync(colsum, 0, NN * sizeof(float), stream);
        k_colsum<<<dim3(NN / 256, 16), 256, 0, stream>>>(Ph, Pl, colsum);
        k_cs<<<1, NN, 0, stream>>>(csz, colsum, csn, h);

        hipMemsetAsync(partial, 0, (size_t)NN * DHD * sizeof(float), stream);
        k_dw<<<dim3(DHD / 64, NN / 128, 16), 256, 0, stream>>>(
            PTh, PTl, XTh + (size_t)h * DHD * BB, XTl + (size_t)h * DHD * BB, partial);
        k_neww_ep<<<dim3(NN / 64, DHD / 64), 256, 0, stream>>>(
            partial, ema + (size_t)h * NN * DHD, csn, NWh, NWl);

        k_quant<<<dim3(DHD / 64, BB / 128, 4), 256, 0, stream>>>(
            Ph, Pl, NWh, NWl, quant, h);
    }

    k_loss<<<BB, 256, 0, stream>>>(inputs, quant, loss);
}